// Round 6
// baseline (236.814 us; speedup 1.0000x reference)
//
#include <hip/hip_runtime.h>
#include <hip/hip_bf16.h>

// SegFormer efficient attention, bf16 MFMA pipeline, round 6.
// B=4 N=4096 C=512 H=8 dh=64 SR=4 -> n_kv=256.
// prep -> conv-GEMM(splitK16) -> reduce+LN -> KV GEMM (writes fragment-ready
// K/V images) -> fused attn (Q-proj via MFMA in-register + swapped QK^T,
// exp2, deferred 1/sum) -> out proj (fp32).

#define EPSV 1e-5f
#define SCALE_Q 0.18033688011112042f   // 0.125 * log2(e)

typedef __attribute__((ext_vector_type(8))) short short8v;   // 8 bf16 = 1 MFMA operand
typedef __attribute__((ext_vector_type(4))) short short4v;
typedef __attribute__((ext_vector_type(4))) float float4v;

static __device__ __forceinline__ ushort f2bf_bits(float x) {
  __hip_bfloat16 h = __float2bfloat16(x);
  return *(ushort*)&h;
}

static __device__ __forceinline__ float4v mfma16(short8v a, short8v b, float4v c) {
  return __builtin_amdgcn_mfma_f32_16x16x32_bf16(a, b, c, 0, 0, 0);
}

// write one staged 16B chunk (8 contiguous-k bf16) into fragment-major LDS.
// lane slot layout: k = 4*(lane>>4) + (j&3) + 16*(j>>2), row-within-frag = lane&15.
static __device__ __forceinline__ void wr_chunk(ushort* lds, int base, int4 v) {
  *(int2*)&lds[base]       = make_int2(v.x, v.y);
  *(int2*)&lds[base + 128] = make_int2(v.z, v.w);
}

// transpose one 32x32 fp32 tile of src[R][512] into dst[512][R] bf16, via LDS.
static __device__ __forceinline__ void tile_t32(const float* __restrict__ src, int srcld,
                                                ushort* __restrict__ dst, int dstld,
                                                int kr0, int c0, int tid, float (*t)[33]) {
  {
    const int r = tid >> 3, c4 = (tid & 7) * 4;
    const float4 v = *(const float4*)&src[(size_t)(kr0 + r) * srcld + c0 + c4];
    t[r][c4 + 0] = v.x; t[r][c4 + 1] = v.y; t[r][c4 + 2] = v.z; t[r][c4 + 3] = v.w;
  }
  __syncthreads();
  {
    const int n = tid >> 3, k4 = (tid & 7) * 4;
    short4v o;
#pragma unroll
    for (int i = 0; i < 4; ++i) o[i] = (short)f2bf_bits(t[k4 + i][n]);
    *(short4v*)&dst[(size_t)(c0 + n) * dstld + kr0 + k4] = o;
  }
}

// ---------------- prep: all casts/transposes/bias in one launch ----------------
__global__ __launch_bounds__(256)
void prep(const float* __restrict__ x, const float* __restrict__ wq,
          const float* __restrict__ wk, const float* __restrict__ wv,
          const float* __restrict__ wp, const float* __restrict__ wsr,
          const float* __restrict__ bk, const float* __restrict__ bv,
          ushort* __restrict__ xbf, ushort* __restrict__ wqT,
          ushort* __restrict__ wkvT, ushort* __restrict__ wpT,
          ushort* __restrict__ wsrT, float* __restrict__ bkv) {
  __shared__ float t[32][33];
  const int bid = blockIdx.x, tid = threadIdx.x;
  if (bid < 4096) {
    const int i = bid * 256 + tid;
    const float4* s4 = (const float4*)x;
    const float4 a = s4[2 * i], b = s4[2 * i + 1];
    short8v v;
    v[0] = (short)f2bf_bits(a.x); v[1] = (short)f2bf_bits(a.y);
    v[2] = (short)f2bf_bits(a.z); v[3] = (short)f2bf_bits(a.w);
    v[4] = (short)f2bf_bits(b.x); v[5] = (short)f2bf_bits(b.y);
    v[6] = (short)f2bf_bits(b.z); v[7] = (short)f2bf_bits(b.w);
    *(short8v*)&xbf[(size_t)i * 8] = v;
  } else if (bid < 8192) {
    const int tI = bid - 4096;
    const int kr0 = (tI & 255) * 32, c0 = (tI >> 8) * 32;
    tile_t32(wsr, 512, wsrT, 8192, kr0, c0, tid, t);
  } else if (bid < 9216) {
    const int wsel = (bid - 8192) >> 8;
    const int tI = (bid - 8192) & 255;
    const int kr0 = (tI & 15) * 32, c0 = (tI >> 4) * 32;
    const float* src = wsel == 0 ? wq : wsel == 1 ? wk : wsel == 2 ? wv : wp;
    ushort* dst = wsel == 0 ? wqT : wsel == 1 ? wkvT : wsel == 2 ? (wkvT + 262144) : wpT;
    tile_t32(src, 512, dst, 512, kr0, c0, tid, t);
  } else {
    const int i4 = tid * 4;
    const float4 v = (i4 < 512) ? *(const float4*)&bk[i4] : *(const float4*)&bv[i4 - 512];
    *(float4*)&bkv[i4] = v;
  }
}

// ---------------- generic bf16 MFMA GEMM ----------------
// C[M,N] = A[M,K] @ BT[N,K]^T (+bias)*scale.  128x128 tile, BK=32, 4 waves.
// MODE 0: fp32 out. MODE 2: KV image out (outp = kimg; vimg = kimg+524288).
template<int MODE>
__global__ __launch_bounds__(256)
void gemm_bf(const ushort* __restrict__ A, const ushort* __restrict__ BT,
             const float* __restrict__ bias, void* __restrict__ outp,
             int M, int N, int K, float scale) {
  __shared__ ushort lds[8192];
  const int tid = threadIdx.x;
  const int wave = tid >> 6, lane = tid & 63;
  const int wm = wave >> 1, wn = wave & 1;
  const int bm = blockIdx.x * 128, bn = blockIdx.y * 128;
  const int lid = lane & 15, lg = lane >> 4;
  const int r0 = tid >> 2, c8 = tid & 3;
  const int g0 = 2 * (c8 & 1), h2 = c8 >> 1;
  const int c0 = c8 * 8;
  const int basew = ((r0 >> 4) * 64 + 16 * g0 + (r0 & 15)) * 8 + h2 * 4;
  float4v acc[4][4];
  const float4v zf = {0.f, 0.f, 0.f, 0.f};
#pragma unroll
  for (int mi = 0; mi < 4; ++mi)
#pragma unroll
    for (int ni = 0; ni < 4; ++ni) acc[mi][ni] = zf;
  const ushort* Ar0 = A + (size_t)(bm + r0) * K;
  const ushort* Ar1 = Ar0 + (size_t)64 * K;
  const ushort* Br0 = BT + (size_t)(bn + r0) * K;
  const ushort* Br1 = Br0 + (size_t)64 * K;
  const int NK = K >> 5;
  int koff = c0;
  int4 pa0 = *(const int4*)(Ar0 + koff), pa1 = *(const int4*)(Ar1 + koff);
  int4 pb0 = *(const int4*)(Br0 + koff), pb1 = *(const int4*)(Br1 + koff);
  for (int kb = 0; kb < NK; ++kb) {
    wr_chunk(lds, basew, pa0);
    wr_chunk(lds, basew + 2048, pa1);
    wr_chunk(lds, basew + 4096, pb0);
    wr_chunk(lds, basew + 6144, pb1);
    __syncthreads();
    if (kb + 1 < NK) {
      koff += 32;
      pa0 = *(const int4*)(Ar0 + koff); pa1 = *(const int4*)(Ar1 + koff);
      pb0 = *(const int4*)(Br0 + koff); pb1 = *(const int4*)(Br1 + koff);
    }
    short8v af[4], bfr[4];
#pragma unroll
    for (int mi = 0; mi < 4; ++mi)
      af[mi] = *(const short8v*)&lds[((wm * 4 + mi) * 64 + lane) * 8];
#pragma unroll
    for (int ni = 0; ni < 4; ++ni)
      bfr[ni] = *(const short8v*)&lds[4096 + ((wn * 4 + ni) * 64 + lane) * 8];
#pragma unroll
    for (int mi = 0; mi < 4; ++mi)
#pragma unroll
      for (int ni = 0; ni < 4; ++ni) acc[mi][ni] = mfma16(af[mi], bfr[ni], acc[mi][ni]);
    __syncthreads();
  }
  float bvv[4];
#pragma unroll
  for (int ni = 0; ni < 4; ++ni) bvv[ni] = bias[bn + wn * 64 + ni * 16 + lid];
#pragma unroll
  for (int mi = 0; mi < 4; ++mi)
#pragma unroll
    for (int ni = 0; ni < 4; ++ni) {
      const int col = bn + wn * 64 + ni * 16 + lid;
#pragma unroll
      for (int reg = 0; reg < 4; ++reg) {
        const int row = bm + wm * 64 + mi * 16 + 4 * lg + reg;
        const float v = (acc[mi][ni][reg] + bvv[ni]) * scale;
        if (MODE == 0) {
          ((float*)outp)[(size_t)row * N + col] = v;
        } else {
          // fragment-image scatter: kimg slot for QK^T A-frags, vimg for PV B-frags
          ushort* img = (ushort*)outp;
          const int bb = row >> 8, kv = row & 255;
          if (col < 512) {
            const int hh = col >> 6, d = col & 63;
            img[(size_t)(bb * 8 + hh) * 16384 +
                ((kv >> 4) * 2 + (d >> 5)) * 512 +
                ((kv & 15) + (((d >> 2) & 3) << 4)) * 8 +
                (d & 3) + (((d >> 4) & 1) << 2)] = f2bf_bits(v);
          } else {
            const int c2 = col - 512;
            const int hh = c2 >> 6, d = c2 & 63;
            (img + 524288)[(size_t)(bb * 8 + hh) * 16384 +
                ((d >> 4) * 8 + (kv >> 5)) * 512 +
                ((d & 15) + (((kv >> 2) & 3) << 4)) * 8 +
                (kv & 3) + (((kv >> 4) & 1) << 2)] = f2bf_bits(v);
          }
        }
      }
    }
}

// ---------------- conv as gathered GEMM, split-K z=16, fp32 partials ----------------
static __device__ __forceinline__ int4 ld_patch(const ushort* xbf, int b, int oh, int ow, int kg) {
  const int ij = kg >> 9, ci = kg & 511;
  const int n = (oh * 4 + (ij >> 2)) * 64 + ow * 4 + (ij & 3);
  return *(const int4*)(xbf + ((size_t)b * 4096 + n) * 512 + ci);
}

__global__ __launch_bounds__(256)
void conv_bf(const ushort* __restrict__ xbf, const ushort* __restrict__ wsrT,
             float* __restrict__ part) {
  __shared__ ushort lds[8192];
  const int tid = threadIdx.x;
  const int wave = tid >> 6, lane = tid & 63;
  const int wm = wave >> 1, wn = wave & 1;
  const int bm = blockIdx.x * 128, bn = blockIdx.y * 128, z = blockIdx.z;
  const int lid = lane & 15, lg = lane >> 4;
  const int r0 = tid >> 2, c8 = tid & 3;
  const int g0 = 2 * (c8 & 1), h2 = c8 >> 1;
  const int c0 = c8 * 8;
  const int basew = ((r0 >> 4) * 64 + 16 * g0 + (r0 & 15)) * 8 + h2 * 4;
  const int p0 = bm + r0, p1 = p0 + 64;
  const int b0 = p0 >> 8, oh0 = (p0 & 255) >> 4, ow0 = p0 & 15;
  const int b1 = p1 >> 8, oh1 = (p1 & 255) >> 4, ow1 = p1 & 15;
  const ushort* Br0 = wsrT + (size_t)(bn + r0) * 8192;
  const ushort* Br1 = Br0 + (size_t)64 * 8192;
  float4v acc[4][4];
  const float4v zf = {0.f, 0.f, 0.f, 0.f};
#pragma unroll
  for (int mi = 0; mi < 4; ++mi)
#pragma unroll
    for (int ni = 0; ni < 4; ++ni) acc[mi][ni] = zf;
  int kg = z * 512 + c0;
  int4 pa0 = ld_patch(xbf, b0, oh0, ow0, kg);
  int4 pa1 = ld_patch(xbf, b1, oh1, ow1, kg);
  int4 pb0 = *(const int4*)(Br0 + kg);
  int4 pb1 = *(const int4*)(Br1 + kg);
  for (int kb = 0; kb < 16; ++kb) {
    wr_chunk(lds, basew, pa0);
    wr_chunk(lds, basew + 2048, pa1);
    wr_chunk(lds, basew + 4096, pb0);
    wr_chunk(lds, basew + 6144, pb1);
    __syncthreads();
    if (kb < 15) {
      kg += 32;
      pa0 = ld_patch(xbf, b0, oh0, ow0, kg);
      pa1 = ld_patch(xbf, b1, oh1, ow1, kg);
      pb0 = *(const int4*)(Br0 + kg);
      pb1 = *(const int4*)(Br1 + kg);
    }
    short8v af[4], bfr[4];
#pragma unroll
    for (int mi = 0; mi < 4; ++mi)
      af[mi] = *(const short8v*)&lds[((wm * 4 + mi) * 64 + lane) * 8];
#pragma unroll
    for (int ni = 0; ni < 4; ++ni)
      bfr[ni] = *(const short8v*)&lds[4096 + ((wn * 4 + ni) * 64 + lane) * 8];
#pragma unroll
    for (int mi = 0; mi < 4; ++mi)
#pragma unroll
      for (int ni = 0; ni < 4; ++ni) acc[mi][ni] = mfma16(af[mi], bfr[ni], acc[mi][ni]);
    __syncthreads();
  }
#pragma unroll
  for (int mi = 0; mi < 4; ++mi)
#pragma unroll
    for (int ni = 0; ni < 4; ++ni)
#pragma unroll
      for (int reg = 0; reg < 4; ++reg)
        part[(size_t)(z * 1024 + bm + wm * 64 + mi * 16 + 4 * lg + reg) * 512 +
             bn + wn * 64 + ni * 16 + lid] = acc[mi][ni][reg];
}

// ---------------- reduce conv partials + bias, LayerNorm -> bf16 ----------------
__global__ __launch_bounds__(256)
void reduce_ln(const float* __restrict__ part, const float* __restrict__ bsr,
               const float* __restrict__ gamma, const float* __restrict__ beta,
               ushort* __restrict__ xln) {
  const int wave = threadIdx.x >> 6;
  const int lane = threadIdx.x & 63;
  const int row = blockIdx.x * 4 + wave;
  const int c = lane * 8;
  float v[8];
  {
    const float4 a = *(const float4*)&bsr[c];
    const float4 b = *(const float4*)&bsr[c + 4];
    v[0] = a.x; v[1] = a.y; v[2] = a.z; v[3] = a.w;
    v[4] = b.x; v[5] = b.y; v[6] = b.z; v[7] = b.w;
  }
#pragma unroll
  for (int z = 0; z < 16; ++z) {
    const float* pr = &part[((size_t)z * 1024 + row) * 512 + c];
    const float4 a = *(const float4*)pr;
    const float4 b = *(const float4*)(pr + 4);
    v[0] += a.x; v[1] += a.y; v[2] += a.z; v[3] += a.w;
    v[4] += b.x; v[5] += b.y; v[6] += b.z; v[7] += b.w;
  }
  float sum = 0.f;
#pragma unroll
  for (int i = 0; i < 8; ++i) sum += v[i];
#pragma unroll
  for (int off = 32; off >= 1; off >>= 1) sum += __shfl_xor(sum, off);
  const float mu = sum * (1.0f / 512.0f);
  float sq = 0.f;
#pragma unroll
  for (int i = 0; i < 8; ++i) { v[i] -= mu; sq += v[i] * v[i]; }
#pragma unroll
  for (int off = 32; off >= 1; off >>= 1) sq += __shfl_xor(sq, off);
  const float rs = rsqrtf(sq * (1.0f / 512.0f) + EPSV);
  const float4 g1 = *(const float4*)&gamma[c];
  const float4 g2 = *(const float4*)&gamma[c + 4];
  const float4 e1 = *(const float4*)&beta[c];
  const float4 e2 = *(const float4*)&beta[c + 4];
  const float g[8] = {g1.x, g1.y, g1.z, g1.w, g2.x, g2.y, g2.z, g2.w};
  const float e[8] = {e1.x, e1.y, e1.z, e1.w, e2.x, e2.y, e2.z, e2.w};
  short8v ov;
#pragma unroll
  for (int i = 0; i < 8; ++i) ov[i] = (short)f2bf_bits(v[i] * rs * g[i] + e[i]);
  *(short8v*)&xln[(size_t)row * 512 + c] = ov;
}

// ---------------- fused attention with in-register Q projection ----------------
// grid (32 bh, 32 qt), 4 waves, wave owns 32 q-rows.
// Phase A: Q^T = mfma(wq-frags, x-frags) -> acc IS the B-frag layout for QK^T.
// Phase B: stage K image (linear copy), QK^T, softmax (exp2, deferred 1/sum).
// Phase C: stage V image (loads issued early), PV, normalize at store.
__global__ __launch_bounds__(256)
void attn_fused(const ushort* __restrict__ xbf, const ushort* __restrict__ wqT,
                const float* __restrict__ bq, const ushort* __restrict__ kvimg,
                ushort* __restrict__ attno) {
  __shared__ ushort kv_lds[22528];           // [0,16384): K/V image; [16384,22528): Q staging
  const int bh = blockIdx.x, qt = blockIdx.y;
  const int b = bh >> 3, h = bh & 7;
  const int tid = threadIdx.x;
  const int wave = tid >> 6, lane = tid & 63;
  const int lid = lane & 15, lg = lane >> 4;
  const ushort* kimg = kvimg + (size_t)bh * 16384;
  const ushort* vimg = kvimg + 524288 + (size_t)bh * 16384;
  // issue K image loads early (written to LDS after Q phase)
  int4 kreg[8];
#pragma unroll
  for (int c = 0; c < 8; ++c)
    kreg[c] = *(const int4*)(kimg + (c * 256 + tid) * 8);
  // ---- Phase A: Q^T via MFMA ----
  const int r0 = tid >> 2, c8 = tid & 3;
  const int g0 = 2 * (c8 & 1), h2 = c8 >> 1;
  const int basew = ((r0 >> 4) * 64 + 16 * g0 + (r0 & 15)) * 8 + h2 * 4;
  ushort* qs = kv_lds + 16384;
  const ushort* Xr0 = xbf + (size_t)(b * 4096 + qt * 128 + r0) * 512;
  const ushort* Xr1 = Xr0 + (size_t)64 * 512;
  const ushort* Wr  = wqT + (size_t)(h * 64 + r0) * 512;
  float4v accq[4][2];
  const float4v zf = {0.f, 0.f, 0.f, 0.f};
#pragma unroll
  for (int dd = 0; dd < 4; ++dd) { accq[dd][0] = zf; accq[dd][1] = zf; }
  int koff = c8 * 8;
  int4 px0 = *(const int4*)(Xr0 + koff);
  int4 px1 = *(const int4*)(Xr1 + koff);
  int4 pw  = *(const int4*)(Wr + koff);
  for (int kt = 0; kt < 16; ++kt) {
    wr_chunk(qs, basew, px0);
    wr_chunk(qs, basew + 2048, px1);
    wr_chunk(qs, basew + 4096, pw);
    __syncthreads();
    if (kt < 15) {
      koff += 32;
      px0 = *(const int4*)(Xr0 + koff);
      px1 = *(const int4*)(Xr1 + koff);
      pw  = *(const int4*)(Wr + koff);
    }
    const short8v xf0 = *(const short8v*)&qs[((wave * 2 + 0) * 64 + lane) * 8];
    const short8v xf1 = *(const short8v*)&qs[((wave * 2 + 1) * 64 + lane) * 8];
#pragma unroll
    for (int dd = 0; dd < 4; ++dd) {
      const short8v wf = *(const short8v*)&qs[4096 + (dd * 64 + lane) * 8];
      accq[dd][0] = mfma16(wf, xf0, accq[dd][0]);
      accq[dd][1] = mfma16(wf, xf1, accq[dd][1]);
    }
    __syncthreads();
  }
  // bias + scale -> qfr (Q B-frags; layout identity: C-layout == B-frag layout)
  short8v qfr[2][2];
#pragma unroll
  for (int t = 0; t < 2; ++t)
#pragma unroll
    for (int odd = 0; odd < 2; ++odd) {
      const int dd = 2 * t + odd;
      const float4 b4 = *(const float4*)&bq[h * 64 + dd * 16 + 4 * lg];
      const float bb[4] = {b4.x, b4.y, b4.z, b4.w};
#pragma unroll
      for (int qf = 0; qf < 2; ++qf)
#pragma unroll
        for (int reg = 0; reg < 4; ++reg)
          qfr[qf][t][reg + 4 * odd] =
              (short)f2bf_bits((accq[dd][qf][reg] + bb[reg]) * SCALE_Q);
    }
  // ---- Phase B: K image -> LDS (linear), QK^T ----
#pragma unroll
  for (int c = 0; c < 8; ++c)
    *(int4*)&kv_lds[(c * 256 + tid) * 8] = kreg[c];
  __syncthreads();
  float4v s[16][2];
#pragma unroll
  for (int kvf = 0; kvf < 16; ++kvf) { s[kvf][0] = zf; s[kvf][1] = zf; }
#pragma unroll
  for (int kvf = 0; kvf < 16; ++kvf)
#pragma unroll
    for (int t = 0; t < 2; ++t) {
      const short8v ka = *(const short8v*)&kv_lds[((kvf * 2 + t) * 64 + lane) * 8];
      s[kvf][0] = mfma16(ka, qfr[0][t], s[kvf][0]);
      s[kvf][1] = mfma16(ka, qfr[1][t], s[kvf][1]);
    }
  // issue V image loads (overlap with softmax)
  int4 vreg[8];
#pragma unroll
  for (int c = 0; c < 8; ++c)
    vreg[c] = *(const int4*)(vimg + (c * 256 + tid) * 8);
  __syncthreads();            // all waves done reading K
#pragma unroll
  for (int c = 0; c < 8; ++c)
    *(int4*)&kv_lds[(c * 256 + tid) * 8] = vreg[c];
  // ---- softmax over kv; scores pre-scaled by log2e ----
  float inv[2];
#pragma unroll
  for (int qf = 0; qf < 2; ++qf) {
    float m = -1e30f;
#pragma unroll
    for (int kvf = 0; kvf < 16; ++kvf)
#pragma unroll
      for (int e = 0; e < 4; ++e) m = fmaxf(m, s[kvf][qf][e]);
    m = fmaxf(m, __shfl_xor(m, 16));
    m = fmaxf(m, __shfl_xor(m, 32));
    float sum = 0.f;
#pragma unroll
    for (int kvf = 0; kvf < 16; ++kvf)
#pragma unroll
      for (int e = 0; e < 4; ++e) {
        const float p = __builtin_amdgcn_exp2f(s[kvf][qf][e] - m);
        s[kvf][qf][e] = p;
        sum += p;
      }
    sum += __shfl_xor(sum, 16);
    sum += __shfl_xor(sum, 32);
    inv[qf] = 1.0f / sum;
  }
  __syncthreads();            // V image ready
  // ---- Phase C: PV (unnormalized P) ----
  float4v o[2][4];
#pragma unroll
  for (int qf = 0; qf < 2; ++qf)
#pragma unroll
    for (int nf = 0; nf < 4; ++nf) o[qf][nf] = zf;
#pragma unroll
  for (int t = 0; t < 8; ++t) {
    short8v vb[4];
#pragma unroll
    for (int nf = 0; nf < 4; ++nf)
      vb[nf] = *(const short8v*)&kv_lds[((nf * 8 + t) * 64 + lane) * 8];
#pragma unroll
    for (int qf = 0; qf < 2; ++qf) {
      short8v pa;
#pragma unroll
      for (int j = 0; j < 4; ++j) {
        pa[j]     = (short)f2bf_bits(s[2 * t][qf][j]);
        pa[4 + j] = (short)f2bf_bits(s[2 * t + 1][qf][j]);
      }
#pragma unroll
      for (int nf = 0; nf < 4; ++nf) o[qf][nf] = mfma16(pa, vb[nf], o[qf][nf]);
    }
  }
  // ---- normalize at output ----
  const int qrow0 = qt * 128 + wave * 32;
#pragma unroll
  for (int qf = 0; qf < 2; ++qf) {
    float sc[4];
#pragma unroll
    for (int reg = 0; reg < 4; ++reg) sc[reg] = __shfl(inv[qf], 4 * lg + reg);
#pragma unroll
    for (int nf = 0; nf < 4; ++nf)
#pragma unroll
      for (int reg = 0; reg < 4; ++reg) {
        const int q = qrow0 + qf * 16 + 4 * lg + reg;
        const int c = h * 64 + nf * 16 + lid;
        attno[(size_t)(b * 4096 + q) * 512 + c] = f2bf_bits(o[qf][nf][reg] * sc[reg]);
      }
  }
}

extern "C" void kernel_launch(void* const* d_in, const int* in_sizes, int n_in,
                              void* d_out, int out_size, void* d_ws, size_t ws_size,
                              hipStream_t stream) {
  const float* x     = (const float*)d_in[0];
  const float* wq    = (const float*)d_in[1];
  const float* bq    = (const float*)d_in[2];
  const float* wk    = (const float*)d_in[3];
  const float* bk    = (const float*)d_in[4];
  const float* wv    = (const float*)d_in[5];
  const float* bv    = (const float*)d_in[6];
  const float* wsr   = (const float*)d_in[7];
  const float* bsr   = (const float*)d_in[8];
  const float* gamma = (const float*)d_in[9];
  const float* beta  = (const float*)d_in[10];
  const float* wp    = (const float*)d_in[11];
  const float* bp    = (const float*)d_in[12];
  float* out = (float*)d_out;

  char* w = (char*)d_ws;
  ushort* xbf   = (ushort*)(w);                  // 16,777,216 B
  ushort* attno = (ushort*)(w + 16777216);       // 16,777,216
  float*  part  = (float*) (w + 33554432);       // 33,554,432 (z=16)
  ushort* wsrT  = (ushort*)(w + 67108864);       //  8,388,608
  ushort* wqT   = (ushort*)(w + 75497472);       //    524,288
  ushort* wpT   = (ushort*)(w + 76021760);       //    524,288
  ushort* wkvT  = (ushort*)(w + 76546048);       //  1,048,576
  ushort* xln   = (ushort*)(w + 77594624);       //  1,048,576
  ushort* kvimg = (ushort*)(w + 78643200);       //  2,097,152 (K img 1MB + V img 1MB)
  float*  bkv   = (float*) (w + 80740352);       //      4,096

  prep<<<9217, 256, 0, stream>>>(x, wq, wk, wv, wp, wsr, bk, bv,
                                 xbf, wqT, wkvT, wpT, wsrT, bkv);
  conv_bf<<<dim3(8, 4, 16), 256, 0, stream>>>(xbf, wsrT, part);
  reduce_ln<<<256, 256, 0, stream>>>(part, bsr, gamma, beta, xln);
  gemm_bf<2><<<dim3(8, 8), 256, 0, stream>>>(xln, wkvT, bkv, kvimg, 1024, 1024, 512, 1.0f);
  attn_fused<<<dim3(32, 32), 256, 0, stream>>>(xbf, wqT, bq, kvimg, attno);
  gemm_bf<0><<<dim3(128, 4), 256, 0, stream>>>(attno, wpT, bp, out, 16384, 512, 512, 1.0f);
}

// Round 7
// 231.816 us; speedup vs baseline: 1.0216x; 1.0216x over previous
//
#include <hip/hip_runtime.h>
#include <hip/hip_bf16.h>

// SegFormer efficient attention, round 7: fragment-image pipeline, LDS-free GEMMs.
// B=4 N=4096 C=512 H=8 dh=64 SR=4 -> n_kv=256.
// prep(xbf + ximg + weight B-images) -> conv(LDS, unchanged) -> reduce_ln(->xln A-image)
//   -> KV gemm_img (->kvimg) -> Q gemm_img (->qimg B-image) -> attn_img (LDS-free,
//   ->oimg A-image) -> out-proj gemm_img (fp32 out).

#define EPSV 1e-5f
#define SCALE_Q 0.18033688011112042f   // 0.125 * log2(e)

typedef __attribute__((ext_vector_type(8))) short short8v;
typedef __attribute__((ext_vector_type(4))) short short4v;
typedef __attribute__((ext_vector_type(4))) float float4v;

static __device__ __forceinline__ ushort f2bf_bits(float x) {
  __hip_bfloat16 h = __float2bfloat16(x);
  return *(ushort*)&h;
}

static __device__ __forceinline__ float4v mfma16(short8v a, short8v b, float4v c) {
  return __builtin_amdgcn_mfma_f32_16x16x32_bf16(a, b, c, 0, 0, 0);
}

// canonical fragment-image index (ushorts). row-dim tiled by 128, k by 32.
// frag f=(row>>4)&7 holds rows f*16+lid; lane=lid+16*lg; elem j: k=4*lg+(j&3)+16*(j>>2).
static __device__ __forceinline__ size_t img_idx(int row, int k, int KC) {
  const int rt = row >> 7, kc = k >> 5, f = (row >> 4) & 7, lid = row & 15;
  const int k32 = k & 31, lg = (k32 >> 2) & 3, j = (k32 & 3) + ((k32 >> 4) & 1) * 4;
  return ((size_t)(rt * KC + kc) * 8 + f) * 512 + (lid + 16 * lg) * 8 + j;
}

// write one staged 16B chunk into fragment-major LDS (conv only).
static __device__ __forceinline__ void wr_chunk(ushort* lds, int base, int4 v) {
  *(int2*)&lds[base]       = make_int2(v.x, v.y);
  *(int2*)&lds[base + 128] = make_int2(v.z, v.w);
}

// ---------------- prep ----------------
// [0,4096): x -> xbf (row-major) + ximg (A-image)
// [4096,8192): wsr -> wsrT row-major (conv)
// [8192,9216): wq/wk/wv/wp -> B-images
// 9216: bkv concat
__global__ __launch_bounds__(256)
void prep(const float* __restrict__ x, const float* __restrict__ wq,
          const float* __restrict__ wk, const float* __restrict__ wv,
          const float* __restrict__ wp, const float* __restrict__ wsr,
          const float* __restrict__ bk, const float* __restrict__ bv,
          ushort* __restrict__ xbf, ushort* __restrict__ ximg,
          ushort* __restrict__ wqimg, ushort* __restrict__ wkvimg,
          ushort* __restrict__ wpimg, ushort* __restrict__ wsrT,
          float* __restrict__ bkv) {
  __shared__ float t[32][33];
  const int bid = blockIdx.x, tid = threadIdx.x;
  if (bid < 4096) {
    const int i = bid * 256 + tid;
    const float4* s4 = (const float4*)x;
    const float4 a = s4[2 * i], b = s4[2 * i + 1];
    short8v v;
    v[0] = (short)f2bf_bits(a.x); v[1] = (short)f2bf_bits(a.y);
    v[2] = (short)f2bf_bits(a.z); v[3] = (short)f2bf_bits(a.w);
    v[4] = (short)f2bf_bits(b.x); v[5] = (short)f2bf_bits(b.y);
    v[6] = (short)f2bf_bits(b.z); v[7] = (short)f2bf_bits(b.w);
    *(short8v*)&xbf[(size_t)i * 8] = v;
    // A-image write: row = i>>6, cols c..c+7
    const int row = i >> 6, c = (i & 63) * 8;
    const int rt = row >> 7, f = (row >> 4) & 7, lid = row & 15;
    const int kc = c >> 5, k32 = c & 31, lg0 = (k32 >> 2) & 3, j0 = ((k32 >> 4) & 1) * 4;
    ushort* basep = ximg + ((size_t)(rt * 16 + kc) * 8 + f) * 512 + j0;
    const int4 vi = *(const int4*)&v;
    *(int2*)&basep[(lid + 16 * lg0) * 8] = make_int2(vi.x, vi.y);
    *(int2*)&basep[(lid + 16 * (lg0 + 1)) * 8] = make_int2(vi.z, vi.w);
  } else if (bid < 8192) {
    const int tI = bid - 4096;
    const int kr0 = (tI & 255) * 32, c0 = (tI >> 8) * 32;
    {
      const int r = tid >> 3, c4 = (tid & 7) * 4;
      const float4 v = *(const float4*)&wsr[(size_t)(kr0 + r) * 512 + c0 + c4];
      t[r][c4 + 0] = v.x; t[r][c4 + 1] = v.y; t[r][c4 + 2] = v.z; t[r][c4 + 3] = v.w;
    }
    __syncthreads();
    {
      const int n = tid >> 3, k4 = (tid & 7) * 4;
      short4v o;
#pragma unroll
      for (int i = 0; i < 4; ++i) o[i] = (short)f2bf_bits(t[k4 + i][n]);
      *(short4v*)&wsrT[(size_t)(c0 + n) * 8192 + kr0 + k4] = o;
    }
  } else if (bid < 9216) {
    const int wsel = (bid - 8192) >> 8;
    const int tI = (bid - 8192) & 255;
    const int kr0 = (tI & 15) * 32, c0 = (tI >> 4) * 32;
    const float* src = wsel == 0 ? wq : wsel == 1 ? wk : wsel == 2 ? wv : wp;
    ushort* dst = wsel == 0 ? wqimg : wsel == 3 ? wpimg : wkvimg;
    const int colbase = (wsel == 2) ? 512 : 0;
    {
      const int r = tid >> 3, c4 = (tid & 7) * 4;
      const float4 v = *(const float4*)&src[(size_t)(kr0 + r) * 512 + c0 + c4];
      t[r][c4 + 0] = v.x; t[r][c4 + 1] = v.y; t[r][c4 + 2] = v.z; t[r][c4 + 3] = v.w;
    }
    __syncthreads();
    {
      const int n = tid >> 3, k4 = (tid & 7) * 4;
      const int col = colbase + c0 + n, k = kr0 + k4;
      short4v o;
#pragma unroll
      for (int i = 0; i < 4; ++i) o[i] = (short)f2bf_bits(t[k4 + i][n]);
      // j0..j0+3 contiguous at img_idx(col, k, 16)
      *(short4v*)&dst[img_idx(col, k, 16)] = o;
    }
  } else {
    const int i4 = tid * 4;
    const float4 v = (i4 < 512) ? *(const float4*)&bk[i4] : *(const float4*)&bv[i4 - 512];
    *(float4*)&bkv[i4] = v;
  }
}

// ---------------- conv as gathered GEMM, split-K z=16 (unchanged) ----------------
static __device__ __forceinline__ int4 ld_patch(const ushort* xbf, int b, int oh, int ow, int kg) {
  const int ij = kg >> 9, ci = kg & 511;
  const int n = (oh * 4 + (ij >> 2)) * 64 + ow * 4 + (ij & 3);
  return *(const int4*)(xbf + ((size_t)b * 4096 + n) * 512 + ci);
}

__global__ __launch_bounds__(256)
void conv_bf(const ushort* __restrict__ xbf, const ushort* __restrict__ wsrT,
             float* __restrict__ part) {
  __shared__ ushort lds[8192];
  const int tid = threadIdx.x;
  const int wave = tid >> 6, lane = tid & 63;
  const int wm = wave >> 1, wn = wave & 1;
  const int bm = blockIdx.x * 128, bn = blockIdx.y * 128, z = blockIdx.z;
  const int lid = lane & 15, lg = lane >> 4;
  const int r0 = tid >> 2, c8 = tid & 3;
  const int g0 = 2 * (c8 & 1), h2 = c8 >> 1;
  const int c0 = c8 * 8;
  const int basew = ((r0 >> 4) * 64 + 16 * g0 + (r0 & 15)) * 8 + h2 * 4;
  const int p0 = bm + r0, p1 = p0 + 64;
  const int b0 = p0 >> 8, oh0 = (p0 & 255) >> 4, ow0 = p0 & 15;
  const int b1 = p1 >> 8, oh1 = (p1 & 255) >> 4, ow1 = p1 & 15;
  const ushort* Br0 = wsrT + (size_t)(bn + r0) * 8192;
  const ushort* Br1 = Br0 + (size_t)64 * 8192;
  float4v acc[4][4];
  const float4v zf = {0.f, 0.f, 0.f, 0.f};
#pragma unroll
  for (int mi = 0; mi < 4; ++mi)
#pragma unroll
    for (int ni = 0; ni < 4; ++ni) acc[mi][ni] = zf;
  int kg = z * 512 + c0;
  int4 pa0 = ld_patch(xbf, b0, oh0, ow0, kg);
  int4 pa1 = ld_patch(xbf, b1, oh1, ow1, kg);
  int4 pb0 = *(const int4*)(Br0 + kg);
  int4 pb1 = *(const int4*)(Br1 + kg);
  for (int kb = 0; kb < 16; ++kb) {
    wr_chunk(lds, basew, pa0);
    wr_chunk(lds, basew + 2048, pa1);
    wr_chunk(lds, basew + 4096, pb0);
    wr_chunk(lds, basew + 6144, pb1);
    __syncthreads();
    if (kb < 15) {
      kg += 32;
      pa0 = ld_patch(xbf, b0, oh0, ow0, kg);
      pa1 = ld_patch(xbf, b1, oh1, ow1, kg);
      pb0 = *(const int4*)(Br0 + kg);
      pb1 = *(const int4*)(Br1 + kg);
    }
    short8v af[4], bfr[4];
#pragma unroll
    for (int mi = 0; mi < 4; ++mi)
      af[mi] = *(const short8v*)&lds[((wm * 4 + mi) * 64 + lane) * 8];
#pragma unroll
    for (int ni = 0; ni < 4; ++ni)
      bfr[ni] = *(const short8v*)&lds[4096 + ((wn * 4 + ni) * 64 + lane) * 8];
#pragma unroll
    for (int mi = 0; mi < 4; ++mi)
#pragma unroll
      for (int ni = 0; ni < 4; ++ni) acc[mi][ni] = mfma16(af[mi], bfr[ni], acc[mi][ni]);
    __syncthreads();
  }
#pragma unroll
  for (int mi = 0; mi < 4; ++mi)
#pragma unroll
    for (int ni = 0; ni < 4; ++ni)
#pragma unroll
      for (int reg = 0; reg < 4; ++reg)
        part[(size_t)(z * 1024 + bm + wm * 64 + mi * 16 + 4 * lg + reg) * 512 +
             bn + wn * 64 + ni * 16 + lid] = acc[mi][ni][reg];
}

// ---------------- reduce conv partials + bias + LayerNorm -> xln A-image ----------------
__global__ __launch_bounds__(256)
void reduce_ln(const float* __restrict__ part, const float* __restrict__ bsr,
               const float* __restrict__ gamma, const float* __restrict__ beta,
               ushort* __restrict__ xlnimg) {
  const int wave = threadIdx.x >> 6;
  const int lane = threadIdx.x & 63;
  const int row = blockIdx.x * 4 + wave;
  const int c = lane * 8;
  float v[8];
  {
    const float4 a = *(const float4*)&bsr[c];
    const float4 b = *(const float4*)&bsr[c + 4];
    v[0] = a.x; v[1] = a.y; v[2] = a.z; v[3] = a.w;
    v[4] = b.x; v[5] = b.y; v[6] = b.z; v[7] = b.w;
  }
#pragma unroll
  for (int z = 0; z < 16; ++z) {
    const float* pr = &part[((size_t)z * 1024 + row) * 512 + c];
    const float4 a = *(const float4*)pr;
    const float4 b = *(const float4*)(pr + 4);
    v[0] += a.x; v[1] += a.y; v[2] += a.z; v[3] += a.w;
    v[4] += b.x; v[5] += b.y; v[6] += b.z; v[7] += b.w;
  }
  float sum = 0.f;
#pragma unroll
  for (int i = 0; i < 8; ++i) sum += v[i];
#pragma unroll
  for (int off = 32; off >= 1; off >>= 1) sum += __shfl_xor(sum, off);
  const float mu = sum * (1.0f / 512.0f);
  float sq = 0.f;
#pragma unroll
  for (int i = 0; i < 8; ++i) { v[i] -= mu; sq += v[i] * v[i]; }
#pragma unroll
  for (int off = 32; off >= 1; off >>= 1) sq += __shfl_xor(sq, off);
  const float rs = rsqrtf(sq * (1.0f / 512.0f) + EPSV);
  const float4 g1 = *(const float4*)&gamma[c];
  const float4 g2 = *(const float4*)&gamma[c + 4];
  const float4 e1 = *(const float4*)&beta[c];
  const float4 e2 = *(const float4*)&beta[c + 4];
  const float g[8] = {g1.x, g1.y, g1.z, g1.w, g2.x, g2.y, g2.z, g2.w};
  const float e[8] = {e1.x, e1.y, e1.z, e1.w, e2.x, e2.y, e2.z, e2.w};
  short8v ov;
#pragma unroll
  for (int i = 0; i < 8; ++i) ov[i] = (short)f2bf_bits(v[i] * rs * g[i] + e[i]);
  // A-image write (M=1024, KC=16)
  const int rt = row >> 7, f = (row >> 4) & 7, lid = row & 15;
  const int kc = c >> 5, k32 = c & 31, lg0 = (k32 >> 2) & 3, j0 = ((k32 >> 4) & 1) * 4;
  ushort* basep = xlnimg + ((size_t)(rt * 16 + kc) * 8 + f) * 512 + j0;
  const int4 vi = *(const int4*)&ov;
  *(int2*)&basep[(lid + 16 * lg0) * 8] = make_int2(vi.x, vi.y);
  *(int2*)&basep[(lid + 16 * (lg0 + 1)) * 8] = make_int2(vi.z, vi.w);
}

// ---------------- LDS-free fragment-image GEMM ----------------
// C[M,N] = A@B^T (+bias, *scale). 128x128 block, 4 waves (2x2 of 64x64), KC k-chunks.
// MODE 0: fp32 row-major out (N=512). MODE 2: kvimg epilogue. MODE 3: qimg epilogue.
template<int MODE>
__global__ __launch_bounds__(256)
void gemm_img(const ushort* __restrict__ Aimg, const ushort* __restrict__ Bimg,
              const float* __restrict__ bias, void* __restrict__ outp, float scale) {
  constexpr int KC = 16;
  const int tid = threadIdx.x;
  const int wave = tid >> 6, lane = tid & 63;
  const int wm = wave >> 1, wn = wave & 1;
  const int rt = blockIdx.x, ct = blockIdx.y;
  const int lid = lane & 15, lg = lane >> 4;
  const ushort* Ab = Aimg + ((size_t)rt * KC * 8 + wm * 4) * 512 + lane * 8;
  const ushort* Bb = Bimg + ((size_t)ct * KC * 8 + wn * 4) * 512 + lane * 8;
  float4v acc[4][4];
  const float4v zf = {0.f, 0.f, 0.f, 0.f};
#pragma unroll
  for (int mi = 0; mi < 4; ++mi)
#pragma unroll
    for (int ni = 0; ni < 4; ++ni) acc[mi][ni] = zf;
#pragma unroll
  for (int kb = 0; kb < KC; ++kb) {
    short8v af[4], bf[4];
#pragma unroll
    for (int mi = 0; mi < 4; ++mi)
      af[mi] = *(const short8v*)(Ab + (size_t)kb * 4096 + mi * 512);
#pragma unroll
    for (int ni = 0; ni < 4; ++ni)
      bf[ni] = *(const short8v*)(Bb + (size_t)kb * 4096 + ni * 512);
#pragma unroll
    for (int mi = 0; mi < 4; ++mi)
#pragma unroll
      for (int ni = 0; ni < 4; ++ni) acc[mi][ni] = mfma16(af[mi], bf[ni], acc[mi][ni]);
  }
  float bvv[4];
#pragma unroll
  for (int ni = 0; ni < 4; ++ni) bvv[ni] = bias[ct * 128 + wn * 64 + ni * 16 + lid];
#pragma unroll
  for (int mi = 0; mi < 4; ++mi)
#pragma unroll
    for (int ni = 0; ni < 4; ++ni) {
      const int col = ct * 128 + wn * 64 + ni * 16 + lid;
#pragma unroll
      for (int reg = 0; reg < 4; ++reg) {
        const int row = rt * 128 + wm * 64 + mi * 16 + 4 * lg + reg;
        const float v = (acc[mi][ni][reg] + bvv[ni]) * scale;
        if (MODE == 0) {
          ((float*)outp)[(size_t)row * 512 + col] = v;
        } else if (MODE == 2) {
          // KV fragment images (proven r6 mapping)
          ushort* img = (ushort*)outp;
          const int bb = row >> 8, kv = row & 255;
          if (col < 512) {
            const int hh = col >> 6, d = col & 63;
            img[(size_t)(bb * 8 + hh) * 16384 +
                ((kv >> 4) * 2 + (d >> 5)) * 512 +
                ((kv & 15) + (((d >> 2) & 3) << 4)) * 8 +
                (d & 3) + (((d >> 4) & 1) << 2)] = f2bf_bits(v);
          } else {
            const int c2 = col - 512;
            const int hh = c2 >> 6, d = c2 & 63;
            (img + 524288)[(size_t)(bb * 8 + hh) * 16384 +
                ((d >> 4) * 8 + (kv >> 5)) * 512 +
                ((d & 15) + (((kv >> 2) & 3) << 4)) * 8 +
                (kv & 3) + (((kv >> 4) & 1) << 2)] = f2bf_bits(v);
          }
        } else {
          // Q B-operand image: [bh][qt][wave][qf][t][lane][8]
          ushort* img = (ushort*)outp;
          const int bq_ = row >> 12, n = row & 4095;
          const int qtt = n >> 7, nn = n & 127;
          const int wv_ = nn >> 5, qf = (nn >> 4) & 1, lidq = nn & 15;
          const int h = col >> 6, d = col & 63, tt = d >> 5, d32 = d & 31;
          const int lgq = (d32 >> 2) & 3, jq = (d32 & 3) + ((d32 >> 4) & 1) * 4;
          img[((size_t)(((bq_ * 8 + h) * 32 + qtt) * 4 + wv_) * 4 + qf * 2 + tt) * 512 +
              (lidq + 16 * lgq) * 8 + jq] = f2bf_bits(v);
        }
      }
    }
}

// ---------------- LDS-free fused attention ----------------
// grid (32 bh, 32 qt), 4 waves x 32 q-rows. All operands read as fragments from images.
__global__ __launch_bounds__(256)
void attn_img(const ushort* __restrict__ qimg, const ushort* __restrict__ kvimg,
              ushort* __restrict__ oimg) {
  const int bh = blockIdx.x, qt = blockIdx.y;
  const int b = bh >> 3, h = bh & 7;
  const int tid = threadIdx.x;
  const int wave = tid >> 6, lane = tid & 63;
  const int lid = lane & 15, lg = lane >> 4;
  const ushort* kb_ = kvimg + (size_t)bh * 16384;
  const ushort* vb_ = kvimg + 524288 + (size_t)bh * 16384;
  const ushort* qb_ = qimg + ((size_t)((bh * 32 + qt) * 4 + wave) * 4) * 512 + lane * 8;
  short8v qfr[2][2];
#pragma unroll
  for (int qf = 0; qf < 2; ++qf)
#pragma unroll
    for (int t = 0; t < 2; ++t)
      qfr[qf][t] = *(const short8v*)(qb_ + (qf * 2 + t) * 512);
  // ---- QK^T (S^T in acc) ----
  float4v s[16][2];
  const float4v zf = {0.f, 0.f, 0.f, 0.f};
#pragma unroll
  for (int kvf = 0; kvf < 16; ++kvf) { s[kvf][0] = zf; s[kvf][1] = zf; }
#pragma unroll
  for (int kvf = 0; kvf < 16; ++kvf)
#pragma unroll
    for (int t = 0; t < 2; ++t) {
      const short8v ka = *(const short8v*)(kb_ + ((kvf * 2 + t) * 64 + lane) * 8);
      s[kvf][0] = mfma16(ka, qfr[0][t], s[kvf][0]);
      s[kvf][1] = mfma16(ka, qfr[1][t], s[kvf][1]);
    }
  // ---- softmax over kv (scores pre-scaled by log2e) ----
  float inv[2];
#pragma unroll
  for (int qf = 0; qf < 2; ++qf) {
    float m = -1e30f;
#pragma unroll
    for (int kvf = 0; kvf < 16; ++kvf)
#pragma unroll
      for (int e = 0; e < 4; ++e) m = fmaxf(m, s[kvf][qf][e]);
    m = fmaxf(m, __shfl_xor(m, 16));
    m = fmaxf(m, __shfl_xor(m, 32));
    float sum = 0.f;
#pragma unroll
    for (int kvf = 0; kvf < 16; ++kvf)
#pragma unroll
      for (int e = 0; e < 4; ++e) {
        const float p = __builtin_amdgcn_exp2f(s[kvf][qf][e] - m);
        s[kvf][qf][e] = p;
        sum += p;
      }
    sum += __shfl_xor(sum, 16);
    sum += __shfl_xor(sum, 32);
    inv[qf] = 1.0f / sum;
  }
  // ---- PV (unnormalized P) ----
  float4v o[2][4];
#pragma unroll
  for (int qf = 0; qf < 2; ++qf)
#pragma unroll
    for (int nf = 0; nf < 4; ++nf) o[qf][nf] = zf;
#pragma unroll
  for (int t = 0; t < 8; ++t) {
    short8v vb[4];
#pragma unroll
    for (int nf = 0; nf < 4; ++nf)
      vb[nf] = *(const short8v*)(vb_ + ((nf * 8 + t) * 64 + lane) * 8);
#pragma unroll
    for (int qf = 0; qf < 2; ++qf) {
      short8v pa;
#pragma unroll
      for (int j = 0; j < 4; ++j) {
        pa[j]     = (short)f2bf_bits(s[2 * t][qf][j]);
        pa[4 + j] = (short)f2bf_bits(s[2 * t + 1][qf][j]);
      }
#pragma unroll
      for (int nf = 0; nf < 4; ++nf) o[qf][nf] = mfma16(pa, vb[nf], o[qf][nf]);
    }
  }
  // ---- normalize + store as A-image for out-proj (M=16384, KC=16) ----
  const int rt_o = b * 32 + qt;
#pragma unroll
  for (int qf = 0; qf < 2; ++qf) {
    float sc[4];
#pragma unroll
    for (int reg = 0; reg < 4; ++reg) sc[reg] = __shfl(inv[qf], 4 * lg + reg);
    const int f_o = wave * 2 + qf;
#pragma unroll
    for (int nf = 0; nf < 4; ++nf) {
      const int colc = h * 64 + nf * 16 + lid;
      const int kc = colc >> 5, k32 = colc & 31;
      const int lgk = (k32 >> 2) & 3, jk = (k32 & 3) + ((k32 >> 4) & 1) * 4;
      ushort* basep = oimg + ((size_t)(rt_o * 16 + kc) * 8 + f_o) * 512 + 16 * lgk * 8 + jk;
#pragma unroll
      for (int reg = 0; reg < 4; ++reg)
        basep[(4 * lg + reg) * 8] = f2bf_bits(o[qf][nf][reg] * sc[reg]);
    }
  }
}

extern "C" void kernel_launch(void* const* d_in, const int* in_sizes, int n_in,
                              void* d_out, int out_size, void* d_ws, size_t ws_size,
                              hipStream_t stream) {
  const float* x     = (const float*)d_in[0];
  const float* wq    = (const float*)d_in[1];
  const float* bq    = (const float*)d_in[2];
  const float* wk    = (const float*)d_in[3];
  const float* bk    = (const float*)d_in[4];
  const float* wv    = (const float*)d_in[5];
  const float* bv    = (const float*)d_in[6];
  const float* wsr   = (const float*)d_in[7];
  const float* bsr   = (const float*)d_in[8];
  const float* gamma = (const float*)d_in[9];
  const float* beta  = (const float*)d_in[10];
  const float* wp    = (const float*)d_in[11];
  const float* bp    = (const float*)d_in[12];
  float* out = (float*)d_out;

  char* w = (char*)d_ws;
  ushort* xbf    = (ushort*)(w);                 // 16,777,216 B
  ushort* ximg   = (ushort*)(w + 16777216);      // 16,777,216
  float*  part   = (float*) (w + 33554432);      // 33,554,432 (conv partials, early)
  ushort* qimg   = (ushort*)(w + 33554432);      // 16,777,216 (aliases part; part dead)
  ushort* oimg   = (ushort*)(w + 50331648);      // 16,777,216 (aliases part 2nd half)
  ushort* wsrT   = (ushort*)(w + 67108864);      //  8,388,608
  ushort* wqimg  = (ushort*)(w + 75497472);      //    524,288
  ushort* wpimg  = (ushort*)(w + 76021760);      //    524,288
  ushort* wkvimg = (ushort*)(w + 76546048);      //  1,048,576
  ushort* xlnimg = (ushort*)(w + 77594624);      //  1,048,576
  ushort* kvimg  = (ushort*)(w + 78643200);      //  2,097,152
  float*  bkv    = (float*) (w + 80740352);      //      4,096

  prep<<<9217, 256, 0, stream>>>(x, wq, wk, wv, wp, wsr, bk, bv,
                                 xbf, ximg, wqimg, wkvimg, wpimg, wsrT, bkv);
  conv_bf<<<dim3(8, 4, 16), 256, 0, stream>>>(xbf, wsrT, part);
  reduce_ln<<<256, 256, 0, stream>>>(part, bsr, gamma, beta, xlnimg);
  gemm_img<2><<<dim3(8, 8), 256, 0, stream>>>(xlnimg, wkvimg, bkv, kvimg, 1.0f);
  gemm_img<3><<<dim3(128, 4), 256, 0, stream>>>(ximg, wqimg, bq, qimg, SCALE_Q);
  attn_img<<<dim3(32, 32), 256, 0, stream>>>(qimg, kvimg, oimg);
  gemm_img<0><<<dim3(128, 4), 256, 0, stream>>>(oimg, wpimg, bp, out, 1.0f);
}

// Round 9
// 229.264 us; speedup vs baseline: 1.0329x; 1.0111x over previous
//
#include <hip/hip_runtime.h>
#include <hip/hip_bf16.h>

// SegFormer efficient attention, round 8 (resubmit): fragment images + global_load_lds.
// B=4 N=4096 C=512 H=8 dh=64 SR=4 -> n_kv=256.
// prep(images) -> [conv || Q-GEMM] (one launch) -> reduce_ln -> KV GEMM -> attn (LDS-free)
//   -> out proj. GEMMs stage linearly from fragment images via global_load_lds (m97 pattern).

#define EPSV 1e-5f
#define SCALE_Q 0.18033688011112042f   // 0.125 * log2(e)

typedef __attribute__((ext_vector_type(8))) short short8v;
typedef __attribute__((ext_vector_type(4))) short short4v;
typedef __attribute__((ext_vector_type(4))) float float4v;

static __device__ __forceinline__ ushort f2bf_bits(float x) {
  __hip_bfloat16 h = __float2bfloat16(x);
  return *(ushort*)&h;
}

static __device__ __forceinline__ float4v mfma16(short8v a, short8v b, float4v c) {
  return __builtin_amdgcn_mfma_f32_16x16x32_bf16(a, b, c, 0, 0, 0);
}

// canonical fragment-image index. frag f=(row>>4)&7 holds rows f*16+lid within a
// 128-row tile; lane=lid+16*lg; elem j: k=4*lg+(j&3)+16*(j>>2).
static __device__ __forceinline__ size_t img_idx(int row, int k, int KC) {
  const int rt = row >> 7, kc = k >> 5, f = (row >> 4) & 7, lid = row & 15;
  const int k32 = k & 31, lg = (k32 >> 2) & 3, j = (k32 & 3) + ((k32 >> 4) & 1) * 4;
  return ((size_t)(rt * KC + kc) * 8 + f) * 512 + (lid + 16 * lg) * 8 + j;
}

// scatter one 16B chunk (8 contiguous-k bf16) into fragment-major LDS (conv A only).
static __device__ __forceinline__ void wr_chunk(ushort* lds, int base, int4 v) {
  *(int2*)&lds[base]       = make_int2(v.x, v.y);
  *(int2*)&lds[base + 128] = make_int2(v.z, v.w);
}

// async global->LDS, 16B per lane. l must be wave-uniform; HW adds lane*16.
static __device__ __forceinline__ void gl_lds16(const ushort* g, ushort* l) {
  __builtin_amdgcn_global_load_lds(
      (const __attribute__((address_space(1))) void*)g,
      (__attribute__((address_space(3))) void*)l, 16, 0, 0);
}

// ---------------- prep ----------------
// [0,4096): x -> xbf (row-major) + ximg (A-image, KC=16)
// [4096,8192): wsr -> B-image (KC=256)
// [8192,9216): wq/wk/wv/wp -> B-images (KC=16)
// 9216: bkv concat
__global__ __launch_bounds__(256)
void prep(const float* __restrict__ x, const float* __restrict__ wq,
          const float* __restrict__ wk, const float* __restrict__ wv,
          const float* __restrict__ wp, const float* __restrict__ wsr,
          const float* __restrict__ bk, const float* __restrict__ bv,
          ushort* __restrict__ xbf, ushort* __restrict__ ximg,
          ushort* __restrict__ wqimg, ushort* __restrict__ wkvimg,
          ushort* __restrict__ wpimg, ushort* __restrict__ wsrimg,
          float* __restrict__ bkv) {
  __shared__ float t[32][33];
  const int bid = blockIdx.x, tid = threadIdx.x;
  if (bid < 4096) {
    const int i = bid * 256 + tid;
    const float4* s4 = (const float4*)x;
    const float4 a = s4[2 * i], b = s4[2 * i + 1];
    short8v v;
    v[0] = (short)f2bf_bits(a.x); v[1] = (short)f2bf_bits(a.y);
    v[2] = (short)f2bf_bits(a.z); v[3] = (short)f2bf_bits(a.w);
    v[4] = (short)f2bf_bits(b.x); v[5] = (short)f2bf_bits(b.y);
    v[6] = (short)f2bf_bits(b.z); v[7] = (short)f2bf_bits(b.w);
    *(short8v*)&xbf[(size_t)i * 8] = v;
    const int row = i >> 6, c = (i & 63) * 8;
    const int rt = row >> 7, f = (row >> 4) & 7, lid = row & 15;
    const int kc = c >> 5, k32 = c & 31, lg0 = (k32 >> 2) & 3, j0 = ((k32 >> 4) & 1) * 4;
    ushort* basep = ximg + ((size_t)(rt * 16 + kc) * 8 + f) * 512 + j0;
    const int4 vi = *(const int4*)&v;
    *(int2*)&basep[(lid + 16 * lg0) * 8] = make_int2(vi.x, vi.y);
    *(int2*)&basep[(lid + 16 * (lg0 + 1)) * 8] = make_int2(vi.z, vi.w);
  } else if (bid < 8192) {
    const int tI = bid - 4096;
    const int kr0 = (tI & 255) * 32, c0 = (tI >> 8) * 32;
    {
      const int r = tid >> 3, c4 = (tid & 7) * 4;
      const float4 v = *(const float4*)&wsr[(size_t)(kr0 + r) * 512 + c0 + c4];
      t[r][c4 + 0] = v.x; t[r][c4 + 1] = v.y; t[r][c4 + 2] = v.z; t[r][c4 + 3] = v.w;
    }
    __syncthreads();
    {
      const int n = tid >> 3, k4 = (tid & 7) * 4;
      short4v o;
#pragma unroll
      for (int i = 0; i < 4; ++i) o[i] = (short)f2bf_bits(t[k4 + i][n]);
      *(short4v*)&wsrimg[img_idx(c0 + n, kr0 + k4, 256)] = o;
    }
  } else if (bid < 9216) {
    const int wsel = (bid - 8192) >> 8;
    const int tI = (bid - 8192) & 255;
    const int kr0 = (tI & 15) * 32, c0 = (tI >> 4) * 32;
    const float* src = wsel == 0 ? wq : wsel == 1 ? wk : wsel == 2 ? wv : wp;
    ushort* dst = wsel == 0 ? wqimg : wsel == 3 ? wpimg : wkvimg;
    const int colbase = (wsel == 2) ? 512 : 0;
    {
      const int r = tid >> 3, c4 = (tid & 7) * 4;
      const float4 v = *(const float4*)&src[(size_t)(kr0 + r) * 512 + c0 + c4];
      t[r][c4 + 0] = v.x; t[r][c4 + 1] = v.y; t[r][c4 + 2] = v.z; t[r][c4 + 3] = v.w;
    }
    __syncthreads();
    {
      const int n = tid >> 3, k4 = (tid & 7) * 4;
      short4v o;
#pragma unroll
      for (int i = 0; i < 4; ++i) o[i] = (short)f2bf_bits(t[k4 + i][n]);
      *(short4v*)&dst[img_idx(colbase + c0 + n, kr0 + k4, 16)] = o;
    }
  } else {
    const int i4 = tid * 4;
    const float4 v = (i4 < 512) ? *(const float4*)&bk[i4] : *(const float4*)&bv[i4 - 512];
    *(float4*)&bkv[i4] = v;
  }
}

// ---------------- conv || Q-GEMM, one launch ----------------
static __device__ __forceinline__ int4 ld_patch(const ushort* xbf, int b, int oh, int ow, int kg) {
  const int ij = kg >> 9, ci = kg & 511;
  const int n = (oh * 4 + (ij >> 2)) * 64 + ow * 4 + (ij & 3);
  return *(const int4*)(xbf + ((size_t)b * 4096 + n) * 512 + ci);
}

__global__ __launch_bounds__(256)
void convq(const ushort* __restrict__ xbf, const ushort* __restrict__ wsrimg,
           float* __restrict__ part, const ushort* __restrict__ ximg,
           const ushort* __restrict__ wqimg, const float* __restrict__ bq,
           ushort* __restrict__ qimg) {
  __shared__ ushort lds[8192];            // A region [0,4096), B region [4096,8192)
  const int bid = blockIdx.x, tid = threadIdx.x;
  const int wave = tid >> 6, lane = tid & 63;
  const int wm = wave >> 1, wn = wave & 1;
  const int lid = lane & 15, lg = lane >> 4;
  const int s0 = wave * 2;
  float4v acc[4][4];
  const float4v zf = {0.f, 0.f, 0.f, 0.f};
#pragma unroll
  for (int mi = 0; mi < 4; ++mi)
#pragma unroll
    for (int ni = 0; ni < 4; ++ni) acc[mi][ni] = zf;
  if (bid < 512) {
    // ---- conv path: z-split GEMM, A gathered+scattered, B image via gl_lds ----
    const int z = bid >> 5, bm = ((bid >> 2) & 7) * 128, bnn = bid & 3;
    const int r0 = tid >> 2, c8 = tid & 3, c0 = c8 * 8;
    const int g0 = 2 * (c8 & 1), h2 = c8 >> 1;
    const int basew = ((r0 >> 4) * 64 + 16 * g0 + (r0 & 15)) * 8 + h2 * 4;
    const int p0 = bm + r0, p1 = p0 + 64;
    const int b0 = p0 >> 8, oh0 = (p0 & 255) >> 4, ow0 = p0 & 15;
    const int b1 = p1 >> 8, oh1 = (p1 & 255) >> 4, ow1 = p1 & 15;
    const ushort* Bc = wsrimg + ((size_t)(bnn * 256 + z * 16)) * 4096 + s0 * 512 + lane * 8;
    int kg = z * 512 + c0;
    int4 pa0 = ld_patch(xbf, b0, oh0, ow0, kg);
    int4 pa1 = ld_patch(xbf, b1, oh1, ow1, kg);
    for (int kb = 0; kb < 16; ++kb) {
      gl_lds16(Bc + (size_t)kb * 4096,       &lds[4096 + s0 * 512]);
      gl_lds16(Bc + (size_t)kb * 4096 + 512, &lds[4096 + s0 * 512 + 512]);
      wr_chunk(lds, basew, pa0);
      wr_chunk(lds, basew + 2048, pa1);
      __syncthreads();
      if (kb < 15) {
        kg += 32;
        pa0 = ld_patch(xbf, b0, oh0, ow0, kg);
        pa1 = ld_patch(xbf, b1, oh1, ow1, kg);
      }
      short8v af[4], bf[4];
#pragma unroll
      for (int mi = 0; mi < 4; ++mi)
        af[mi] = *(const short8v*)&lds[((wm * 4 + mi) * 64 + lane) * 8];
#pragma unroll
      for (int ni = 0; ni < 4; ++ni)
        bf[ni] = *(const short8v*)&lds[4096 + ((wn * 4 + ni) * 64 + lane) * 8];
#pragma unroll
      for (int mi = 0; mi < 4; ++mi)
#pragma unroll
        for (int ni = 0; ni < 4; ++ni) acc[mi][ni] = mfma16(af[mi], bf[ni], acc[mi][ni]);
      __syncthreads();
    }
#pragma unroll
    for (int mi = 0; mi < 4; ++mi)
#pragma unroll
      for (int ni = 0; ni < 4; ++ni)
#pragma unroll
        for (int reg = 0; reg < 4; ++reg)
          part[(size_t)(z * 1024 + bm + wm * 64 + mi * 16 + 4 * lg + reg) * 512 +
               bnn * 128 + wn * 64 + ni * 16 + lid] = acc[mi][ni][reg];
  } else {
    // ---- Q path: image GEMM via gl_lds, epilogue -> Q B-image ----
    const int qid = bid - 512;
    const int rt = qid >> 2, ct = qid & 3;
    const ushort* Ac = ximg + ((size_t)rt * 16) * 4096 + s0 * 512 + lane * 8;
    const ushort* Bc = wqimg + ((size_t)ct * 16) * 4096 + s0 * 512 + lane * 8;
    for (int kb = 0; kb < 16; ++kb) {
      gl_lds16(Ac + (size_t)kb * 4096,       &lds[s0 * 512]);
      gl_lds16(Ac + (size_t)kb * 4096 + 512, &lds[s0 * 512 + 512]);
      gl_lds16(Bc + (size_t)kb * 4096,       &lds[4096 + s0 * 512]);
      gl_lds16(Bc + (size_t)kb * 4096 + 512, &lds[4096 + s0 * 512 + 512]);
      __syncthreads();
      short8v af[4], bf[4];
#pragma unroll
      for (int mi = 0; mi < 4; ++mi)
        af[mi] = *(const short8v*)&lds[((wm * 4 + mi) * 64 + lane) * 8];
#pragma unroll
      for (int ni = 0; ni < 4; ++ni)
        bf[ni] = *(const short8v*)&lds[4096 + ((wn * 4 + ni) * 64 + lane) * 8];
#pragma unroll
      for (int mi = 0; mi < 4; ++mi)
#pragma unroll
        for (int ni = 0; ni < 4; ++ni) acc[mi][ni] = mfma16(af[mi], bf[ni], acc[mi][ni]);
      __syncthreads();
    }
    float bvv[4];
#pragma unroll
    for (int ni = 0; ni < 4; ++ni) bvv[ni] = bq[ct * 128 + wn * 64 + ni * 16 + lid];
#pragma unroll
    for (int mi = 0; mi < 4; ++mi)
#pragma unroll
      for (int ni = 0; ni < 4; ++ni) {
        const int col = ct * 128 + wn * 64 + ni * 16 + lid;
#pragma unroll
        for (int reg = 0; reg < 4; ++reg) {
          const int row = rt * 128 + wm * 64 + mi * 16 + 4 * lg + reg;
          const float v = (acc[mi][ni][reg] + bvv[ni]) * SCALE_Q;
          const int bq_ = row >> 12, n = row & 4095;
          const int qtt = n >> 7, nn = n & 127;
          const int wv_ = nn >> 5, qf = (nn >> 4) & 1, lidq = nn & 15;
          const int h = col >> 6, d = col & 63, tt = d >> 5, d32 = d & 31;
          const int lgq = (d32 >> 2) & 3, jq = (d32 & 3) + ((d32 >> 4) & 1) * 4;
          qimg[((size_t)(((bq_ * 8 + h) * 32 + qtt) * 4 + wv_) * 4 + qf * 2 + tt) * 512 +
               (lidq + 16 * lgq) * 8 + jq] = f2bf_bits(v);
        }
      }
  }
}

// ---------------- reduce conv partials + bias + LayerNorm -> xln A-image ----------------
__global__ __launch_bounds__(256)
void reduce_ln(const float* __restrict__ part, const float* __restrict__ bsr,
               const float* __restrict__ gamma, const float* __restrict__ beta,
               ushort* __restrict__ xlnimg) {
  const int wave = threadIdx.x >> 6;
  const int lane = threadIdx.x & 63;
  const int row = blockIdx.x * 4 + wave;
  const int c = lane * 8;
  float v[8];
  {
    const float4 a = *(const float4*)&bsr[c];
    const float4 b = *(const float4*)&bsr[c + 4];
    v[0] = a.x; v[1] = a.y; v[2] = a.z; v[3] = a.w;
    v[4] = b.x; v[5] = b.y; v[6] = b.z; v[7] = b.w;
  }
#pragma unroll
  for (int z = 0; z < 16; ++z) {
    const float* pr = &part[((size_t)z * 1024 + row) * 512 + c];
    const float4 a = *(const float4*)pr;
    const float4 b = *(const float4*)(pr + 4);
    v[0] += a.x; v[1] += a.y; v[2] += a.z; v[3] += a.w;
    v[4] += b.x; v[5] += b.y; v[6] += b.z; v[7] += b.w;
  }
  float sum = 0.f;
#pragma unroll
  for (int i = 0; i < 8; ++i) sum += v[i];
#pragma unroll
  for (int off = 32; off >= 1; off >>= 1) sum += __shfl_xor(sum, off);
  const float mu = sum * (1.0f / 512.0f);
  float sq = 0.f;
#pragma unroll
  for (int i = 0; i < 8; ++i) { v[i] -= mu; sq += v[i] * v[i]; }
#pragma unroll
  for (int off = 32; off >= 1; off >>= 1) sq += __shfl_xor(sq, off);
  const float rs = rsqrtf(sq * (1.0f / 512.0f) + EPSV);
  const float4 g1 = *(const float4*)&gamma[c];
  const float4 g2 = *(const float4*)&gamma[c + 4];
  const float4 e1 = *(const float4*)&beta[c];
  const float4 e2 = *(const float4*)&beta[c + 4];
  const float g[8] = {g1.x, g1.y, g1.z, g1.w, g2.x, g2.y, g2.z, g2.w};
  const float e[8] = {e1.x, e1.y, e1.z, e1.w, e2.x, e2.y, e2.z, e2.w};
  short8v ov;
#pragma unroll
  for (int i = 0; i < 8; ++i) ov[i] = (short)f2bf_bits(v[i] * rs * g[i] + e[i]);
  const int rt = row >> 7, f = (row >> 4) & 7, lid = row & 15;
  const int kc = c >> 5, k32 = c & 31, lg0 = (k32 >> 2) & 3, j0 = ((k32 >> 4) & 1) * 4;
  ushort* basep = xlnimg + ((size_t)(rt * 16 + kc) * 8 + f) * 512 + j0;
  const int4 vi = *(const int4*)&ov;
  *(int2*)&basep[(lid + 16 * lg0) * 8] = make_int2(vi.x, vi.y);
  *(int2*)&basep[(lid + 16 * (lg0 + 1)) * 8] = make_int2(vi.z, vi.w);
}

// ---------------- image GEMM with gl_lds staging ----------------
// MODE 0: fp32 row-major out (N=512). MODE 2: kvimg epilogue (vimg = kimg+524288).
template<int MODE>
__global__ __launch_bounds__(256)
void gemm_lds(const ushort* __restrict__ Aimg, const ushort* __restrict__ Bimg,
              const float* __restrict__ bias, void* __restrict__ outp, float scale) {
  __shared__ ushort lds[8192];
  const int tid = threadIdx.x;
  const int wave = tid >> 6, lane = tid & 63;
  const int wm = wave >> 1, wn = wave & 1;
  const int rt = blockIdx.x, ct = blockIdx.y;
  const int lid = lane & 15, lg = lane >> 4;
  const int s0 = wave * 2;
  const ushort* Ac = Aimg + ((size_t)rt * 16) * 4096 + s0 * 512 + lane * 8;
  const ushort* Bc = Bimg + ((size_t)ct * 16) * 4096 + s0 * 512 + lane * 8;
  float4v acc[4][4];
  const float4v zf = {0.f, 0.f, 0.f, 0.f};
#pragma unroll
  for (int mi = 0; mi < 4; ++mi)
#pragma unroll
    for (int ni = 0; ni < 4; ++ni) acc[mi][ni] = zf;
  for (int kb = 0; kb < 16; ++kb) {
    gl_lds16(Ac + (size_t)kb * 4096,       &lds[s0 * 512]);
    gl_lds16(Ac + (size_t)kb * 4096 + 512, &lds[s0 * 512 + 512]);
    gl_lds16(Bc + (size_t)kb * 4096,       &lds[4096 + s0 * 512]);
    gl_lds16(Bc + (size_t)kb * 4096 + 512, &lds[4096 + s0 * 512 + 512]);
    __syncthreads();
    short8v af[4], bf[4];
#pragma unroll
    for (int mi = 0; mi < 4; ++mi)
      af[mi] = *(const short8v*)&lds[((wm * 4 + mi) * 64 + lane) * 8];
#pragma unroll
    for (int ni = 0; ni < 4; ++ni)
      bf[ni] = *(const short8v*)&lds[4096 + ((wn * 4 + ni) * 64 + lane) * 8];
#pragma unroll
    for (int mi = 0; mi < 4; ++mi)
#pragma unroll
      for (int ni = 0; ni < 4; ++ni) acc[mi][ni] = mfma16(af[mi], bf[ni], acc[mi][ni]);
    __syncthreads();
  }
  float bvv[4];
#pragma unroll
  for (int ni = 0; ni < 4; ++ni) bvv[ni] = bias[ct * 128 + wn * 64 + ni * 16 + lid];
#pragma unroll
  for (int mi = 0; mi < 4; ++mi)
#pragma unroll
    for (int ni = 0; ni < 4; ++ni) {
      const int col = ct * 128 + wn * 64 + ni * 16 + lid;
#pragma unroll
      for (int reg = 0; reg < 4; ++reg) {
        const int row = rt * 128 + wm * 64 + mi * 16 + 4 * lg + reg;
        const float v = (acc[mi][ni][reg] + bvv[ni]) * scale;
        if (MODE == 0) {
          ((float*)outp)[(size_t)row * 512 + col] = v;
        } else {
          ushort* img = (ushort*)outp;
          const int bb = row >> 8, kv = row & 255;
          if (col < 512) {
            const int hh = col >> 6, d = col & 63;
            img[(size_t)(bb * 8 + hh) * 16384 +
                ((kv >> 4) * 2 + (d >> 5)) * 512 +
                ((kv & 15) + (((d >> 2) & 3) << 4)) * 8 +
                (d & 3) + (((d >> 4) & 1) << 2)] = f2bf_bits(v);
          } else {
            const int c2 = col - 512;
            const int hh = c2 >> 6, d = c2 & 63;
            (img + 524288)[(size_t)(bb * 8 + hh) * 16384 +
                ((d >> 4) * 8 + (kv >> 5)) * 512 +
                ((d & 15) + (((kv >> 2) & 3) << 4)) * 8 +
                (kv & 3) + (((kv >> 4) & 1) << 2)] = f2bf_bits(v);
          }
        }
      }
    }
}

// ---------------- LDS-free fused attention (r7, verbatim) ----------------
__global__ __launch_bounds__(256)
void attn_img(const ushort* __restrict__ qimg, const ushort* __restrict__ kvimg,
              ushort* __restrict__ oimg) {
  const int bh = blockIdx.x, qt = blockIdx.y;
  const int b = bh >> 3, h = bh & 7;
  const int tid = threadIdx.x;
  const int wave = tid >> 6, lane = tid & 63;
  const int lid = lane & 15, lg = lane >> 4;
  const ushort* kb_ = kvimg + (size_t)bh * 16384;
  const ushort* vb_ = kvimg + 524288 + (size_t)bh * 16384;
  const ushort* qb_ = qimg + ((size_t)((bh * 32 + qt) * 4 + wave) * 4) * 512 + lane * 8;
  short8v qfr[2][2];
#pragma unroll
  for (int qf = 0; qf < 2; ++qf)
#pragma unroll
    for (int t = 0; t < 2; ++t)
      qfr[qf][t] = *(const short8v*)(qb_ + (qf * 2 + t) * 512);
  float4v s[16][2];
  const float4v zf = {0.f, 0.f, 0.f, 0.f};
#pragma unroll
  for (int kvf = 0; kvf < 16; ++kvf) { s[kvf][0] = zf; s[kvf][1] = zf; }
#pragma unroll
  for (int kvf = 0; kvf < 16; ++kvf)
#pragma unroll
    for (int t = 0; t < 2; ++t) {
      const short8v ka = *(const short8v*)(kb_ + ((kvf * 2 + t) * 64 + lane) * 8);
      s[kvf][0] = mfma16(ka, qfr[0][t], s[kvf][0]);
      s[kvf][1] = mfma16(ka, qfr[1][t], s[kvf][1]);
    }
  float inv[2];
#pragma unroll
  for (int qf = 0; qf < 2; ++qf) {
    float m = -1e30f;
#pragma unroll
    for (int kvf = 0; kvf < 16; ++kvf)
#pragma unroll
      for (int e = 0; e < 4; ++e) m = fmaxf(m, s[kvf][qf][e]);
    m = fmaxf(m, __shfl_xor(m, 16));
    m = fmaxf(m, __shfl_xor(m, 32));
    float sum = 0.f;
#pragma unroll
    for (int kvf = 0; kvf < 16; ++kvf)
#pragma unroll
      for (int e = 0; e < 4; ++e) {
        const float p = __builtin_amdgcn_exp2f(s[kvf][qf][e] - m);
        s[kvf][qf][e] = p;
        sum += p;
      }
    sum += __shfl_xor(sum, 16);
    sum += __shfl_xor(sum, 32);
    inv[qf] = 1.0f / sum;
  }
  float4v o[2][4];
#pragma unroll
  for (int qf = 0; qf < 2; ++qf)
#pragma unroll
    for (int nf = 0; nf < 4; ++nf) o[qf][nf] = zf;
#pragma unroll
  for (int t = 0; t < 8; ++t) {
    short8v vb[4];
#pragma unroll
    for (int nf = 0; nf < 4; ++nf)
      vb[nf] = *(const short8v*)(vb_ + ((nf * 8 + t) * 64 + lane) * 8);
#pragma unroll
    for (int qf = 0; qf < 2; ++qf) {
      short8v pa;
#pragma unroll
      for (int j = 0; j < 4; ++j) {
        pa[j]     = (short)f2bf_bits(s[2 * t][qf][j]);
        pa[4 + j] = (short)f2bf_bits(s[2 * t + 1][qf][j]);
      }
#pragma unroll
      for (int nf = 0; nf < 4; ++nf) o[qf][nf] = mfma16(pa, vb[nf], o[qf][nf]);
    }
  }
  const int rt_o = b * 32 + qt;
#pragma unroll
  for (int qf = 0; qf < 2; ++qf) {
    float sc[4];
#pragma unroll
    for (int reg = 0; reg < 4; ++reg) sc[reg] = __shfl(inv[qf], 4 * lg + reg);
    const int f_o = wave * 2 + qf;
#pragma unroll
    for (int nf = 0; nf < 4; ++nf) {
      const int colc = h * 64 + nf * 16 + lid;
      const int kc = colc >> 5, k32 = colc & 31;
      const int lgk = (k32 >> 2) & 3, jk = (k32 & 3) + ((k32 >> 4) & 1) * 4;
      ushort* basep = oimg + ((size_t)(rt_o * 16 + kc) * 8 + f_o) * 512 + 16 * lgk * 8 + jk;
#pragma unroll
      for (int reg = 0; reg < 4; ++reg)
        basep[(4 * lg + reg) * 8] = f2bf_bits(o[qf][nf][reg] * sc[reg]);
    }
  }
}

extern "C" void kernel_launch(void* const* d_in, const int* in_sizes, int n_in,
                              void* d_out, int out_size, void* d_ws, size_t ws_size,
                              hipStream_t stream) {
  const float* x     = (const float*)d_in[0];
  const float* wq    = (const float*)d_in[1];
  const float* bq    = (const float*)d_in[2];
  const float* wk    = (const float*)d_in[3];
  const float* bk    = (const float*)d_in[4];
  const float* wv    = (const float*)d_in[5];
  const float* bv    = (const float*)d_in[6];
  const float* wsr   = (const float*)d_in[7];
  const float* bsr   = (const float*)d_in[8];
  const float* gamma = (const float*)d_in[9];
  const float* beta  = (const float*)d_in[10];
  const float* wp    = (const float*)d_in[11];
  const float* bp    = (const float*)d_in[12];
  float* out = (float*)d_out;

  char* w = (char*)d_ws;                          // no aliasing (conv || Q concurrent)
  ushort* xbf    = (ushort*)(w);                  // 16,777,216 B
  ushort* ximg   = (ushort*)(w + 16777216);       // 16,777,216
  float*  part   = (float*) (w + 33554432);       // 33,554,432 (z=16)
  ushort* qimg   = (ushort*)(w + 67108864);       // 16,777,216
  ushort* oimg   = (ushort*)(w + 83886080);       // 16,777,216
  ushort* wsrimg = (ushort*)(w + 100663296);      //  8,388,608
  ushort* wqimg  = (ushort*)(w + 109051904);      //    524,288
  ushort* wpimg  = (ushort*)(w + 109576192);      //    524,288
  ushort* wkvimg = (ushort*)(w + 110100480);      //  1,048,576
  ushort* xlnimg = (ushort*)(w + 111149056);      //  1,048,576
  ushort* kvimg  = (ushort*)(w + 112197632);      //  2,097,152
  float*  bkv    = (float*) (w + 114294784);      //      4,096

  prep<<<9217, 256, 0, stream>>>(x, wq, wk, wv, wp, wsr, bk, bv,
                                 xbf, ximg, wqimg, wkvimg, wpimg, wsrimg, bkv);
  convq<<<1024, 256, 0, stream>>>(xbf, wsrimg, part, ximg, wqimg, bq, qimg);
  reduce_ln<<<256, 256, 0, stream>>>(part, bsr, gamma, beta, xlnimg);
  gemm_lds<2><<<dim3(8, 8), 256, 0, stream>>>(xlnimg, wkvimg, bkv, kvimg, 1.0f);
  attn_img<<<dim3(32, 32), 256, 0, stream>>>(qimg, kvimg, oimg);
  gemm_lds<0><<<dim3(128, 4), 256, 0, stream>>>(oimg, wpimg, bp, out, 1.0f);
}